// Round 7
// baseline (1115.000 us; speedup 1.0000x reference)
//
#include <hip/hip_runtime.h>
#include <stdint.h>

// STAR fused forward via split-precision bf16x2 MFMA (gfx950).
// V7 = V5 (32-row tile, jj=4, dual-plane H0/H1, 16 waves/CU) +
// NON-TEMPORAL x path: x-frag loads in phase 0, x loads + ws writes in
// prep, and out stores are all nt. Rationale: W0 (4MiB) exactly fills a
// per-XCD L2 and x streaming (256MB/pass) evicts it -> phase-0 B-loads
// bounce to L3 (~600cyc vs ~200). nt keeps weights L2-resident. V6's A/B
// showed L2 *bandwidth* is not binding (halving traffic lost perf via
// occupancy), so this targets L2 *residency* at constant occupancy.
// + unroll hints on tail loops. Bit-identical math.
// Falls back to the verified V1 kernel when ws is too small.

namespace {

typedef __attribute__((ext_vector_type(8))) short bf16x8;
typedef __attribute__((ext_vector_type(4))) float f32x4;
typedef __attribute__((ext_vector_type(4))) unsigned int u32x4;

union Frag { bf16x8 v; unsigned int u[4]; };

// ws byte layout (weights/biases identical to V1 so the fallback is unchanged)
constexpr size_t WS_L0   = 0;                 // 8j*16kc*16nt pairs * 2048B = 4 MiB
constexpr size_t WS_L1   = 4194304;           // 8*8*8 pairs  * 2048B = 1 MiB
constexpr size_t WS_L2   = 5242880;           // 8*4*4 pairs  * 2048B = 256 KiB
constexpr size_t WS_B0   = 5505024;           // 8*256 f32
constexpr size_t WS_B1   = 5513216;           // 8*128 f32
constexpr size_t WS_B2   = 5517312;           // 8*64  f32
constexpr size_t WS_X    = 5519360;           // 4096 rowblk * 16 kc * 2048B = 128 MiB
constexpr size_t WS_TOTAL_BIG = WS_X + (size_t)65536 * 2048; // 139,737,088 B

constexpr int PREP_TOTAL = 1048576 + 262144 + 65536 + 2048 + 1024 + 512; // 1379840

__device__ __forceinline__ void splitpair(float a, float b,
                                          unsigned int& hi, unsigned int& lo) {
    unsigned int ua = __float_as_uint(a);
    unsigned int ub = __float_as_uint(b);
    unsigned int ha = ua & 0xffff0000u;
    unsigned int hb = ub & 0xffff0000u;
    float ra = a - __uint_as_float(ha);
    float rb = b - __uint_as_float(hb);
    hi = (ua >> 16) | hb;
    lo = (__float_as_uint(ra) >> 16) | (__float_as_uint(rb) & 0xffff0000u);
}

// scalar split for the dual-plane epilogues (bit-identical to splitpair)
__device__ __forceinline__ void split16(float v, unsigned short& h, unsigned short& l) {
    unsigned int u = __float_as_uint(v);
    h = (unsigned short)(u >> 16);
    float r = v - __uint_as_float(u & 0xffff0000u);
    l = (unsigned short)(__float_as_uint(r) >> 16);
}

// --- plain-bitop versions (fallback kernel keeps these) ---
__device__ __forceinline__ unsigned int packsplit(float v) {
    unsigned int u = __float_as_uint(v);
    unsigned int h = u & 0xffff0000u;
    float r = v - __uint_as_float(h);
    return h | (__float_as_uint(r) >> 16);
}

__device__ __forceinline__ void unpack2(unsigned int e0, unsigned int e1,
                                        unsigned int& hi, unsigned int& lo) {
    hi = (e0 >> 16) | (e1 & 0xffff0000u);
    lo = (e0 & 0xffffu) | (e1 << 16);
}

// ---------------- prep: fuse sk*dk -> hi/lo bf16 frag-order planes + biases
__global__ void prep_ws(const float* __restrict__ sk0, const float* __restrict__ dk0,
                        const float* __restrict__ sk1, const float* __restrict__ dk1,
                        const float* __restrict__ sk2, const float* __restrict__ dk2,
                        const float* __restrict__ sb0, const float* __restrict__ db0,
                        const float* __restrict__ sb1, const float* __restrict__ db1,
                        const float* __restrict__ sb2, const float* __restrict__ db2,
                        char* __restrict__ ws) {
    int tid = blockIdx.x * 256 + threadIdx.x;
    if (tid < 1048576) {                       // layer 0: [j][k<512][n<256]
        int n = tid & 255, k = (tid >> 8) & 511, j = tid >> 17;
        float wv = sk0[k * 256 + n] * dk0[(size_t)(j * 512 + k) * 256 + n];
        unsigned int u = __float_as_uint(wv);
        unsigned int h = u & 0xffff0000u;
        float r = wv - __uint_as_float(h);
        int pair = (j * 16 + (k >> 5)) * 16 + (n >> 4);
        int lane = (n & 15) | (((k >> 3) & 3) << 4);
        size_t off = WS_L0 + (size_t)pair * 2048 + lane * 16 + (k & 7) * 2;
        *(unsigned short*)(ws + off)        = (unsigned short)(u >> 16);
        *(unsigned short*)(ws + off + 1024) = (unsigned short)(__float_as_uint(r) >> 16);
    } else if (tid < 1310720) {                // layer 1: [j][k<256][n<128]
        int t = tid - 1048576;
        int n = t & 127, k = (t >> 7) & 255, j = t >> 15;
        float wv = sk1[k * 128 + n] * dk1[(size_t)(j * 256 + k) * 128 + n];
        unsigned int u = __float_as_uint(wv);
        unsigned int h = u & 0xffff0000u;
        float r = wv - __uint_as_float(h);
        int pair = (j * 8 + (k >> 5)) * 8 + (n >> 4);
        int lane = (n & 15) | (((k >> 3) & 3) << 4);
        size_t off = WS_L1 + (size_t)pair * 2048 + lane * 16 + (k & 7) * 2;
        *(unsigned short*)(ws + off)        = (unsigned short)(u >> 16);
        *(unsigned short*)(ws + off + 1024) = (unsigned short)(__float_as_uint(r) >> 16);
    } else if (tid < 1376256) {                // layer 2: [j][k<128][n<64]
        int t = tid - 1310720;
        int n = t & 63, k = (t >> 6) & 127, j = t >> 13;
        float wv = sk2[k * 64 + n] * dk2[(size_t)(j * 128 + k) * 64 + n];
        unsigned int u = __float_as_uint(wv);
        unsigned int h = u & 0xffff0000u;
        float r = wv - __uint_as_float(h);
        int pair = (j * 4 + (k >> 5)) * 4 + (n >> 4);
        int lane = (n & 15) | (((k >> 3) & 3) << 4);
        size_t off = WS_L2 + (size_t)pair * 2048 + lane * 16 + (k & 7) * 2;
        *(unsigned short*)(ws + off)        = (unsigned short)(u >> 16);
        *(unsigned short*)(ws + off + 1024) = (unsigned short)(__float_as_uint(r) >> 16);
    } else if (tid < 1378304) {                // bias0: 8*256
        int t = tid - 1376256;
        ((float*)(ws + WS_B0))[t] = sb0[t & 255] + db0[t];
    } else if (tid < 1379328) {                // bias1: 8*128
        int t = tid - 1378304;
        ((float*)(ws + WS_B1))[t] = sb1[t & 127] + db1[t];
    } else if (tid < PREP_TOTAL) {             // bias2: 8*64
        int t = tid - 1379328;
        ((float*)(ws + WS_B2))[t] = sb2[t & 63] + db2[t];
    }
}

// ---------------- prep: split x into FRAGMENT-MAJOR hi/lo bf16 chunks via LDS.
// Block b handles rows b*16..b*16+15 (one rowblk = 16 chunks = 32KB out).
// Chunk (rowblk, kc): 2048B = [hi 1024B][lo 1024B], lane = (r&15)|(q<<4),
// lane's 16B holds k = kc*32 + q*8 + 0..7. Bit-identical to splitpair.
// All global accesses non-temporal: x is read once, ws/x-frag written once.
__global__ __launch_bounds__(256) void prep_xsplit(const float* __restrict__ x,
                                                   char* __restrict__ ws) {
    __shared__ __align__(16) unsigned int xf[8192];  // 32 KiB
    const int b     = blockIdx.x;       // rowblk 0..4095
    const int tid   = threadIdx.x;
    const int row16 = tid >> 4;         // 0..15
    const int seg   = tid & 15;         // = kc

    const f32x4* src = (const f32x4*)(x + ((size_t)b * 16 + row16) * 512 + seg * 32);
    f32x4 a[8];
#pragma unroll
    for (int i = 0; i < 8; ++i) a[i] = __builtin_nontemporal_load(src + i);

    unsigned int hi[16], lo[16];
#pragma unroll
    for (int i = 0; i < 8; ++i) {
        splitpair(a[i].x, a[i].y, hi[2 * i],     lo[2 * i]);
        splitpair(a[i].z, a[i].w, hi[2 * i + 1], lo[2 * i + 1]);
    }
#pragma unroll
    for (int qq = 0; qq < 4; ++qq) {
        const int lane = row16 | (qq << 4);
        const int di = seg * 512 + lane * 4;
        uint4 vh = { hi[qq * 4 + 0], hi[qq * 4 + 1], hi[qq * 4 + 2], hi[qq * 4 + 3] };
        uint4 vl = { lo[qq * 4 + 0], lo[qq * 4 + 1], lo[qq * 4 + 2], lo[qq * 4 + 3] };
        *(uint4*)&xf[di]       = vh;
        *(uint4*)&xf[di + 256] = vl;
    }
    __syncthreads();

    u32x4* dst = (u32x4*)(ws + WS_X + (size_t)b * 32768) + tid * 8;
#pragma unroll
    for (int i = 0; i < 8; ++i)
        __builtin_nontemporal_store(*(const u32x4*)&xf[tid * 32 + i * 4], dst + i);
}

// ---------------- V7 main kernel: 512 thr (8 waves), 32 rows/block, 2048 blocks
__global__ __launch_bounds__(512, 4) void star_mfma_v7(
    const float* __restrict__ ind,  // [65536,8]
    const char* __restrict__ ws,
    float* __restrict__ out)        // [65536,64]
{
    // dual-plane bf16 LDS: stride 264/136 elems -> 528/272B rows (16B aligned)
    __shared__ __align__(16) unsigned short H0hi[32 * 264];
    __shared__ __align__(16) unsigned short H0lo[32 * 264];
    __shared__ __align__(16) unsigned short H1hi[32 * 136];
    __shared__ __align__(16) unsigned short H1lo[32 * 136];
    __shared__ float indS[8 * 33];

    const int tid  = threadIdx.x;
    const int w    = tid >> 6;      // wave 0..7
    const int lane = tid & 63;
    const int c    = lane & 15;
    const int q    = lane >> 4;
    const int b0   = blockIdx.x * 32;
    const int mt2  = w >> 2;        // phase-2 m-tile of this wave
    const int nt2  = w & 3;         // phase-2 n-tile of this wave

    const char* xp  = ws + WS_X;
    const char* wB0 = ws + WS_L0;
    const char* wB1 = ws + WS_L1;
    const char* wB2 = ws + WS_L2;
    const float* bias0 = (const float*)(ws + WS_B0);
    const float* bias1 = (const float*)(ws + WS_B1);
    const float* bias2 = (const float*)(ws + WS_B2);

    if (tid < 256) indS[(tid & 7) * 33 + (tid >> 3)] = ind[(size_t)b0 * 8 + tid];

    const f32x4 z = {0.f, 0.f, 0.f, 0.f};
    f32x4 oacc = z;

    __syncthreads();

    for (int jp = 0; jp < 2; ++jp) {
        // ========== phase 0 for 4 domains at once: X[32,512] @ W0[j][512,256]
        f32x4 acc0[4][2][2];
#pragma unroll
        for (int jj = 0; jj < 4; ++jj)
#pragma unroll
            for (int mt = 0; mt < 2; ++mt)
#pragma unroll
                for (int ntl = 0; ntl < 2; ++ntl) acc0[jj][mt][ntl] = z;

        for (int kc = 0; kc < 16; ++kc) {
            Frag Ahi[2], Alo[2];
#pragma unroll
            for (int mt = 0; mt < 2; ++mt) {
                // x is streamed exactly twice per block with zero L2 reuse:
                // non-temporal keeps W0 (4MiB, massive reuse) L2-resident.
                const u32x4* ap = (const u32x4*)(xp +
                    ((size_t)((blockIdx.x * 2 + mt) * 16 + kc) * 2048) + lane * 16);
                *(u32x4*)Ahi[mt].u = __builtin_nontemporal_load(ap);
                *(u32x4*)Alo[mt].u = __builtin_nontemporal_load(ap + 64); // +1024B
            }
#pragma unroll
            for (int jj = 0; jj < 4; ++jj) {
                const int j = jp * 4 + jj;
#pragma unroll
                for (int ntl = 0; ntl < 2; ++ntl) {
                    const int nt = w * 2 + ntl;
                    const char* pb = wB0 + ((size_t)((j * 16 + kc) * 16 + nt) * 2048) + lane * 16;
                    Frag Bhi, Blo;
                    *(uint4*)Bhi.u = *(const uint4*)pb;
                    *(uint4*)Blo.u = *(const uint4*)(pb + 1024);
#pragma unroll
                    for (int mt = 0; mt < 2; ++mt) {
                        acc0[jj][mt][ntl] = __builtin_amdgcn_mfma_f32_16x16x32_bf16(Ahi[mt].v, Bhi.v, acc0[jj][mt][ntl], 0, 0, 0);
                        acc0[jj][mt][ntl] = __builtin_amdgcn_mfma_f32_16x16x32_bf16(Ahi[mt].v, Blo.v, acc0[jj][mt][ntl], 0, 0, 0);
                        acc0[jj][mt][ntl] = __builtin_amdgcn_mfma_f32_16x16x32_bf16(Alo[mt].v, Bhi.v, acc0[jj][mt][ntl], 0, 0, 0);
                    }
                }
            }
        }

        // ========== per-domain tail: epilogue0 -> phase1 -> phase2 ==========
#pragma unroll
        for (int jj = 0; jj < 4; ++jj) {
            const int j = jp * 4 + jj;

            // epilogue 0: bias + relu -> hi/lo bf16 planes H0[m][k]
#pragma unroll
            for (int ntl = 0; ntl < 2; ++ntl) {
                const int k = w * 32 + ntl * 16 + c;
                const float bv = bias0[j * 256 + k];
#pragma unroll
                for (int mt = 0; mt < 2; ++mt)
#pragma unroll
                    for (int r = 0; r < 4; ++r) {
                        float v = fmaxf(acc0[jj][mt][ntl][r] + bv, 0.f);
                        unsigned short h16, l16;
                        split16(v, h16, l16);
                        const int idx = (mt * 16 + q * 4 + r) * 264 + k;
                        H0hi[idx] = h16;
                        H0lo[idx] = l16;
                    }
            }
            __syncthreads();

            // phase 1: H0[32,256] @ W1[256,128] — direct b128 A-frags
            f32x4 acc1[2]; acc1[0] = z; acc1[1] = z;
#pragma unroll 2
            for (int kc = 0; kc < 8; ++kc) {
                Frag Ahi[2], Alo[2];
#pragma unroll
                for (int mt = 0; mt < 2; ++mt) {
                    const int idx = (mt * 16 + c) * 264 + kc * 32 + q * 8;
                    *(uint4*)Ahi[mt].u = *(const uint4*)&H0hi[idx];
                    *(uint4*)Alo[mt].u = *(const uint4*)&H0lo[idx];
                }
                const char* pb = wB1 + ((size_t)((j * 8 + kc) * 8 + w) * 2048) + lane * 16;
                Frag Bhi, Blo;
                *(uint4*)Bhi.u = *(const uint4*)pb;
                *(uint4*)Blo.u = *(const uint4*)(pb + 1024);
#pragma unroll
                for (int mt = 0; mt < 2; ++mt) {
                    acc1[mt] = __builtin_amdgcn_mfma_f32_16x16x32_bf16(Ahi[mt].v, Bhi.v, acc1[mt], 0, 0, 0);
                    acc1[mt] = __builtin_amdgcn_mfma_f32_16x16x32_bf16(Ahi[mt].v, Blo.v, acc1[mt], 0, 0, 0);
                    acc1[mt] = __builtin_amdgcn_mfma_f32_16x16x32_bf16(Alo[mt].v, Bhi.v, acc1[mt], 0, 0, 0);
                }
            }
            // epilogue 1 -> H1 planes
            {
                const int k = w * 16 + c;
                const float bv = bias1[j * 128 + k];
#pragma unroll
                for (int mt = 0; mt < 2; ++mt)
#pragma unroll
                    for (int r = 0; r < 4; ++r) {
                        float v = fmaxf(acc1[mt][r] + bv, 0.f);
                        unsigned short h16, l16;
                        split16(v, h16, l16);
                        const int idx = (mt * 16 + q * 4 + r) * 136 + k;
                        H1hi[idx] = h16;
                        H1lo[idx] = l16;
                    }
            }
            __syncthreads();

            // phase 2: H1[32,128] @ W2[128,64]; 8 waves cover the 2x4 tile grid
            f32x4 acc2 = z;
#pragma unroll
            for (int kc = 0; kc < 4; ++kc) {
                Frag Ahi, Alo;
                const int idx = (mt2 * 16 + c) * 136 + kc * 32 + q * 8;
                *(uint4*)Ahi.u = *(const uint4*)&H1hi[idx];
                *(uint4*)Alo.u = *(const uint4*)&H1lo[idx];
                const char* pb = wB2 + ((size_t)((j * 4 + kc) * 4 + nt2) * 2048) + lane * 16;
                Frag Bhi, Blo;
                *(uint4*)Bhi.u = *(const uint4*)pb;
                *(uint4*)Blo.u = *(const uint4*)(pb + 1024);
                acc2 = __builtin_amdgcn_mfma_f32_16x16x32_bf16(Ahi.v, Bhi.v, acc2, 0, 0, 0);
                acc2 = __builtin_amdgcn_mfma_f32_16x16x32_bf16(Ahi.v, Blo.v, acc2, 0, 0, 0);
                acc2 = __builtin_amdgcn_mfma_f32_16x16x32_bf16(Alo.v, Bhi.v, acc2, 0, 0, 0);
            }
            // epilogue 2: bias + relu + indicator mix into oacc
            {
                const float bv = bias2[j * 64 + nt2 * 16 + c];
#pragma unroll
                for (int r = 0; r < 4; ++r) {
                    float v = fmaxf(acc2[r] + bv, 0.f);
                    oacc[r] = fmaf(indS[j * 33 + mt2 * 16 + q * 4 + r], v, oacc[r]);
                }
            }
            // Hazard scheme: sync after epi0 orders H0 write->read; sync after
            // epi1 orders H1 write->read and protects next jj's H0 writes.
        }
    }

    // store: out[b0 + mt2*16 + q*4 + r][nt2*16 + c] — nt, no reuse
#pragma unroll
    for (int r = 0; r < 4; ++r)
        __builtin_nontemporal_store(oacc[r],
            &out[(size_t)(b0 + mt2 * 16 + q * 4 + r) * 64 + nt2 * 16 + c]);
}

// ---------------- fallback (verbatim V1): 256 thr, splits x on the fly ----
__global__ __launch_bounds__(256, 3) void star_mfma_fb(
    const float* __restrict__ x,    // [65536,512]
    const float* __restrict__ ind,  // [65536,8]
    const char* __restrict__ ws,
    float* __restrict__ out)        // [65536,64]
{
    __shared__ unsigned int H0s[32 * 260];
    __shared__ unsigned int H1s[32 * 132];
    __shared__ float indS[8 * 33];

    const int tid  = threadIdx.x;
    const int w    = tid >> 6;
    const int lane = tid & 63;
    const int c    = lane & 15;
    const int q    = lane >> 4;
    const int b0   = blockIdx.x * 32;

    const char* wB0 = ws + WS_L0;
    const char* wB1 = ws + WS_L1;
    const char* wB2 = ws + WS_L2;
    const float* bias0 = (const float*)(ws + WS_B0);
    const float* bias1 = (const float*)(ws + WS_B1);
    const float* bias2 = (const float*)(ws + WS_B2);

    indS[(tid & 7) * 33 + (tid >> 3)] = ind[(size_t)b0 * 8 + tid];

    const f32x4 z = {0.f, 0.f, 0.f, 0.f};
    f32x4 oacc[2]; oacc[0] = z; oacc[1] = z;

    __syncthreads();

    for (int j = 0; j < 8; ++j) {
        f32x4 acc0[2][4];
#pragma unroll
        for (int mt = 0; mt < 2; ++mt)
#pragma unroll
            for (int ntl = 0; ntl < 4; ++ntl) acc0[mt][ntl] = z;

        for (int kc = 0; kc < 16; ++kc) {
            Frag Ahi[2], Alo[2];
#pragma unroll
            for (int mt = 0; mt < 2; ++mt) {
                const float* ap = x + (size_t)(b0 + mt * 16 + c) * 512 + kc * 32 + q * 8;
                float4 a0 = *(const float4*)ap;
                float4 a1 = *(const float4*)(ap + 4);
                splitpair(a0.x, a0.y, Ahi[mt].u[0], Alo[mt].u[0]);
                splitpair(a0.z, a0.w, Ahi[mt].u[1], Alo[mt].u[1]);
                splitpair(a1.x, a1.y, Ahi[mt].u[2], Alo[mt].u[2]);
                splitpair(a1.z, a1.w, Ahi[mt].u[3], Alo[mt].u[3]);
            }
#pragma unroll
            for (int ntl = 0; ntl < 4; ++ntl) {
                const int nt = w * 4 + ntl;
                const char* pb = wB0 + ((size_t)((j * 16 + kc) * 16 + nt) * 2048) + lane * 16;
                Frag Bhi, Blo;
                *(uint4*)Bhi.u = *(const uint4*)pb;
                *(uint4*)Blo.u = *(const uint4*)(pb + 1024);
#pragma unroll
                for (int mt = 0; mt < 2; ++mt) {
                    acc0[mt][ntl] = __builtin_amdgcn_mfma_f32_16x16x32_bf16(Ahi[mt].v, Bhi.v, acc0[mt][ntl], 0, 0, 0);
                    acc0[mt][ntl] = __builtin_amdgcn_mfma_f32_16x16x32_bf16(Ahi[mt].v, Blo.v, acc0[mt][ntl], 0, 0, 0);
                    acc0[mt][ntl] = __builtin_amdgcn_mfma_f32_16x16x32_bf16(Alo[mt].v, Bhi.v, acc0[mt][ntl], 0, 0, 0);
                }
            }
        }
#pragma unroll
        for (int ntl = 0; ntl < 4; ++ntl) {
            const float bv = bias0[j * 256 + w * 64 + ntl * 16 + c];
#pragma unroll
            for (int mt = 0; mt < 2; ++mt)
#pragma unroll
                for (int r = 0; r < 4; ++r) {
                    float v = acc0[mt][ntl][r] + bv;
                    v = fmaxf(v, 0.f);
                    H0s[(mt * 16 + q * 4 + r) * 260 + w * 64 + ntl * 16 + c] = packsplit(v);
                }
        }
        __syncthreads();

        f32x4 acc1[2][2];
#pragma unroll
        for (int mt = 0; mt < 2; ++mt)
#pragma unroll
            for (int ntl = 0; ntl < 2; ++ntl) acc1[mt][ntl] = z;

        for (int kc = 0; kc < 8; ++kc) {
            Frag Ahi[2], Alo[2];
#pragma unroll
            for (int mt = 0; mt < 2; ++mt) {
                const unsigned int* hp = &H0s[(mt * 16 + c) * 260 + kc * 32 + q * 8];
                uint4 e0 = *(const uint4*)hp;
                uint4 e1 = *(const uint4*)(hp + 4);
                unpack2(e0.x, e0.y, Ahi[mt].u[0], Alo[mt].u[0]);
                unpack2(e0.z, e0.w, Ahi[mt].u[1], Alo[mt].u[1]);
                unpack2(e1.x, e1.y, Ahi[mt].u[2], Alo[mt].u[2]);
                unpack2(e1.z, e1.w, Ahi[mt].u[3], Alo[mt].u[3]);
            }
#pragma unroll
            for (int ntl = 0; ntl < 2; ++ntl) {
                const int nt = w * 2 + ntl;
                const char* pb = wB1 + ((size_t)((j * 8 + kc) * 8 + nt) * 2048) + lane * 16;
                Frag Bhi, Blo;
                *(uint4*)Bhi.u = *(const uint4*)pb;
                *(uint4*)Blo.u = *(const uint4*)(pb + 1024);
#pragma unroll
                for (int mt = 0; mt < 2; ++mt) {
                    acc1[mt][ntl] = __builtin_amdgcn_mfma_f32_16x16x32_bf16(Ahi[mt].v, Bhi.v, acc1[mt][ntl], 0, 0, 0);
                    acc1[mt][ntl] = __builtin_amdgcn_mfma_f32_16x16x32_bf16(Ahi[mt].v, Blo.v, acc1[mt][ntl], 0, 0, 0);
                    acc1[mt][ntl] = __builtin_amdgcn_mfma_f32_16x16x32_bf16(Alo[mt].v, Bhi.v, acc1[mt][ntl], 0, 0, 0);
                }
            }
        }
#pragma unroll
        for (int ntl = 0; ntl < 2; ++ntl) {
            const float bv = bias1[j * 128 + w * 32 + ntl * 16 + c];
#pragma unroll
            for (int mt = 0; mt < 2; ++mt)
#pragma unroll
                for (int r = 0; r < 4; ++r) {
                    float v = acc1[mt][ntl][r] + bv;
                    v = fmaxf(v, 0.f);
                    H1s[(mt * 16 + q * 4 + r) * 132 + w * 32 + ntl * 16 + c] = packsplit(v);
                }
        }
        __syncthreads();

        f32x4 acc2[2]; acc2[0] = z; acc2[1] = z;

        for (int kc = 0; kc < 4; ++kc) {
            Frag Ahi[2], Alo[2];
#pragma unroll
            for (int mt = 0; mt < 2; ++mt) {
                const unsigned int* hp = &H1s[(mt * 16 + c) * 132 + kc * 32 + q * 8];
                uint4 e0 = *(const uint4*)hp;
                uint4 e1 = *(const uint4*)(hp + 4);
                unpack2(e0.x, e0.y, Ahi[mt].u[0], Alo[mt].u[0]);
                unpack2(e0.z, e0.w, Ahi[mt].u[1], Alo[mt].u[1]);
                unpack2(e1.x, e1.y, Ahi[mt].u[2], Alo[mt].u[2]);
                unpack2(e1.z, e1.w, Ahi[mt].u[3], Alo[mt].u[3]);
            }
            const char* pb = wB2 + ((size_t)((j * 4 + kc) * 4 + w) * 2048) + lane * 16;
            Frag Bhi, Blo;
            *(uint4*)Bhi.u = *(const uint4*)pb;
            *(uint4*)Blo.u = *(const uint4*)(pb + 1024);
#pragma unroll
            for (int mt = 0; mt < 2; ++mt) {
                acc2[mt] = __builtin_amdgcn_mfma_f32_16x16x32_bf16(Ahi[mt].v, Bhi.v, acc2[mt], 0, 0, 0);
                acc2[mt] = __builtin_amdgcn_mfma_f32_16x16x32_bf16(Ahi[mt].v, Blo.v, acc2[mt], 0, 0, 0);
                acc2[mt] = __builtin_amdgcn_mfma_f32_16x16x32_bf16(Alo[mt].v, Bhi.v, acc2[mt], 0, 0, 0);
            }
        }
        {
            const float bv = bias2[j * 64 + w * 16 + c];
#pragma unroll
            for (int mt = 0; mt < 2; ++mt)
#pragma unroll
                for (int r = 0; r < 4; ++r) {
                    float v = acc2[mt][r] + bv;
                    v = fmaxf(v, 0.f);
                    oacc[mt][r] = fmaf(indS[j * 33 + mt * 16 + q * 4 + r], v, oacc[mt][r]);
                }
        }
    }

#pragma unroll
    for (int mt = 0; mt < 2; ++mt)
#pragma unroll
        for (int r = 0; r < 4; ++r)
            out[(size_t)(b0 + mt * 16 + q * 4 + r) * 64 + w * 16 + c] = oacc[mt][r];
}

} // namespace

extern "C" void kernel_launch(void* const* d_in, const int* in_sizes, int n_in,
                              void* d_out, int out_size, void* d_ws, size_t ws_size,
                              hipStream_t stream) {
    const float* x   = (const float*)d_in[0];
    const float* ind = (const float*)d_in[1];
    const float* sk0 = (const float*)d_in[2];
    const float* sb0 = (const float*)d_in[3];
    const float* dk0 = (const float*)d_in[4];
    const float* db0 = (const float*)d_in[5];
    const float* sk1 = (const float*)d_in[6];
    const float* sb1 = (const float*)d_in[7];
    const float* dk1 = (const float*)d_in[8];
    const float* db1 = (const float*)d_in[9];
    const float* sk2 = (const float*)d_in[10];
    const float* sb2 = (const float*)d_in[11];
    const float* dk2 = (const float*)d_in[12];
    const float* db2 = (const float*)d_in[13];
    char* ws   = (char*)d_ws;
    float* out = (float*)d_out;

    prep_ws<<<dim3((PREP_TOTAL + 255) / 256), dim3(256), 0, stream>>>(
        sk0, dk0, sk1, dk1, sk2, dk2, sb0, db0, sb1, db1, sb2, db2, ws);

    if (ws_size >= WS_TOTAL_BIG) {
        prep_xsplit<<<dim3(4096), dim3(256), 0, stream>>>(x, ws);
        star_mfma_v7<<<dim3(2048), dim3(512), 0, stream>>>(ind, ws, out);
    } else {
        star_mfma_fb<<<dim3(2048), dim3(256), 0, stream>>>(x, ind, ws, out);
    }
}

// Round 8
// 776.792 us; speedup vs baseline: 1.4354x; 1.4354x over previous
//
#include <hip/hip_runtime.h>
#include <stdint.h>

// STAR fused forward via split-precision bf16x2 MFMA (gfx950).
// V8: M=64 rows/block at CONSTANT 16 waves/CU (V6 retry with the resource
// problems fixed). 1024 blocks x 512 thr. Phase-0 B traffic per CU halves
// (each block reads all of W0 once; 4 blocks/CU instead of 8) -> L2 time
// ~125us drops below the 199us phase-0 MFMA floor. Registers kept <=128
// via jj=2 (4 x-passes; x is L3-resident so re-reads are cheap; B traffic
// is jj-independent). LDS kept <=80KB by ALIASING H1 planes onto H0's
// buffer (H0 dead after phase 1) -> 67.6KB -> 2 blocks/CU. Costs 4
// barriers/j instead of 2. All nt load/store reverted (V7: FETCH 2x, dur
// +55us). Bit-identical math. Falls back to V1 kernel when ws too small.

namespace {

typedef __attribute__((ext_vector_type(8))) short bf16x8;
typedef __attribute__((ext_vector_type(4))) float f32x4;

union Frag { bf16x8 v; unsigned int u[4]; };

// ws byte layout (weights/biases identical to V1 so the fallback is unchanged)
constexpr size_t WS_L0   = 0;                 // 8j*16kc*16nt pairs * 2048B = 4 MiB
constexpr size_t WS_L1   = 4194304;           // 8*8*8 pairs  * 2048B = 1 MiB
constexpr size_t WS_L2   = 5242880;           // 8*4*4 pairs  * 2048B = 256 KiB
constexpr size_t WS_B0   = 5505024;           // 8*256 f32
constexpr size_t WS_B1   = 5513216;           // 8*128 f32
constexpr size_t WS_B2   = 5517312;           // 8*64  f32
constexpr size_t WS_X    = 5519360;           // 4096 rowblk * 16 kc * 2048B = 128 MiB
constexpr size_t WS_TOTAL_BIG = WS_X + (size_t)65536 * 2048; // 139,737,088 B

constexpr int PREP_TOTAL = 1048576 + 262144 + 65536 + 2048 + 1024 + 512; // 1379840

__device__ __forceinline__ void splitpair(float a, float b,
                                          unsigned int& hi, unsigned int& lo) {
    unsigned int ua = __float_as_uint(a);
    unsigned int ub = __float_as_uint(b);
    unsigned int ha = ua & 0xffff0000u;
    unsigned int hb = ub & 0xffff0000u;
    float ra = a - __uint_as_float(ha);
    float rb = b - __uint_as_float(hb);
    hi = (ua >> 16) | hb;
    lo = (__float_as_uint(ra) >> 16) | (__float_as_uint(rb) & 0xffff0000u);
}

// scalar split for the dual-plane epilogues (bit-identical to splitpair)
__device__ __forceinline__ void split16(float v, unsigned short& h, unsigned short& l) {
    unsigned int u = __float_as_uint(v);
    h = (unsigned short)(u >> 16);
    float r = v - __uint_as_float(u & 0xffff0000u);
    l = (unsigned short)(__float_as_uint(r) >> 16);
}

// --- plain-bitop versions (fallback kernel keeps these) ---
__device__ __forceinline__ unsigned int packsplit(float v) {
    unsigned int u = __float_as_uint(v);
    unsigned int h = u & 0xffff0000u;
    float r = v - __uint_as_float(h);
    return h | (__float_as_uint(r) >> 16);
}

__device__ __forceinline__ void unpack2(unsigned int e0, unsigned int e1,
                                        unsigned int& hi, unsigned int& lo) {
    hi = (e0 >> 16) | (e1 & 0xffff0000u);
    lo = (e0 & 0xffffu) | (e1 << 16);
}

// ---------------- prep: fuse sk*dk -> hi/lo bf16 frag-order planes + biases
__global__ void prep_ws(const float* __restrict__ sk0, const float* __restrict__ dk0,
                        const float* __restrict__ sk1, const float* __restrict__ dk1,
                        const float* __restrict__ sk2, const float* __restrict__ dk2,
                        const float* __restrict__ sb0, const float* __restrict__ db0,
                        const float* __restrict__ sb1, const float* __restrict__ db1,
                        const float* __restrict__ sb2, const float* __restrict__ db2,
                        char* __restrict__ ws) {
    int tid = blockIdx.x * 256 + threadIdx.x;
    if (tid < 1048576) {                       // layer 0: [j][k<512][n<256]
        int n = tid & 255, k = (tid >> 8) & 511, j = tid >> 17;
        float wv = sk0[k * 256 + n] * dk0[(size_t)(j * 512 + k) * 256 + n];
        unsigned int u = __float_as_uint(wv);
        unsigned int h = u & 0xffff0000u;
        float r = wv - __uint_as_float(h);
        int pair = (j * 16 + (k >> 5)) * 16 + (n >> 4);
        int lane = (n & 15) | (((k >> 3) & 3) << 4);
        size_t off = WS_L0 + (size_t)pair * 2048 + lane * 16 + (k & 7) * 2;
        *(unsigned short*)(ws + off)        = (unsigned short)(u >> 16);
        *(unsigned short*)(ws + off + 1024) = (unsigned short)(__float_as_uint(r) >> 16);
    } else if (tid < 1310720) {                // layer 1: [j][k<256][n<128]
        int t = tid - 1048576;
        int n = t & 127, k = (t >> 7) & 255, j = t >> 15;
        float wv = sk1[k * 128 + n] * dk1[(size_t)(j * 256 + k) * 128 + n];
        unsigned int u = __float_as_uint(wv);
        unsigned int h = u & 0xffff0000u;
        float r = wv - __uint_as_float(h);
        int pair = (j * 8 + (k >> 5)) * 8 + (n >> 4);
        int lane = (n & 15) | (((k >> 3) & 3) << 4);
        size_t off = WS_L1 + (size_t)pair * 2048 + lane * 16 + (k & 7) * 2;
        *(unsigned short*)(ws + off)        = (unsigned short)(u >> 16);
        *(unsigned short*)(ws + off + 1024) = (unsigned short)(__float_as_uint(r) >> 16);
    } else if (tid < 1376256) {                // layer 2: [j][k<128][n<64]
        int t = tid - 1310720;
        int n = t & 63, k = (t >> 6) & 127, j = t >> 13;
        float wv = sk2[k * 64 + n] * dk2[(size_t)(j * 128 + k) * 64 + n];
        unsigned int u = __float_as_uint(wv);
        unsigned int h = u & 0xffff0000u;
        float r = wv - __uint_as_float(h);
        int pair = (j * 4 + (k >> 5)) * 4 + (n >> 4);
        int lane = (n & 15) | (((k >> 3) & 3) << 4);
        size_t off = WS_L2 + (size_t)pair * 2048 + lane * 16 + (k & 7) * 2;
        *(unsigned short*)(ws + off)        = (unsigned short)(u >> 16);
        *(unsigned short*)(ws + off + 1024) = (unsigned short)(__float_as_uint(r) >> 16);
    } else if (tid < 1378304) {                // bias0: 8*256
        int t = tid - 1376256;
        ((float*)(ws + WS_B0))[t] = sb0[t & 255] + db0[t];
    } else if (tid < 1379328) {                // bias1: 8*128
        int t = tid - 1378304;
        ((float*)(ws + WS_B1))[t] = sb1[t & 127] + db1[t];
    } else if (tid < PREP_TOTAL) {             // bias2: 8*64
        int t = tid - 1379328;
        ((float*)(ws + WS_B2))[t] = sb2[t & 63] + db2[t];
    }
}

// ---------------- prep: split x into FRAGMENT-MAJOR hi/lo bf16 chunks via LDS.
// Block b handles rows b*16..b*16+15 (one rowblk = 16 chunks = 32KB out).
// Chunk (rowblk, kc): 2048B = [hi 1024B][lo 1024B], lane = (r&15)|(q<<4),
// lane's 16B holds k = kc*32 + q*8 + 0..7. Bit-identical to splitpair.
__global__ __launch_bounds__(256) void prep_xsplit(const float* __restrict__ x,
                                                   char* __restrict__ ws) {
    __shared__ __align__(16) unsigned int xf[8192];  // 32 KiB
    const int b     = blockIdx.x;       // rowblk 0..4095
    const int tid   = threadIdx.x;
    const int row16 = tid >> 4;         // 0..15
    const int seg   = tid & 15;         // = kc

    const float* src = x + ((size_t)b * 16 + row16) * 512 + seg * 32;
    float4 a[8];
#pragma unroll
    for (int i = 0; i < 8; ++i) a[i] = *(const float4*)(src + i * 4);

    unsigned int hi[16], lo[16];
#pragma unroll
    for (int i = 0; i < 8; ++i) {
        splitpair(a[i].x, a[i].y, hi[2 * i],     lo[2 * i]);
        splitpair(a[i].z, a[i].w, hi[2 * i + 1], lo[2 * i + 1]);
    }
#pragma unroll
    for (int qq = 0; qq < 4; ++qq) {
        const int lane = row16 | (qq << 4);
        const int di = seg * 512 + lane * 4;
        uint4 vh = { hi[qq * 4 + 0], hi[qq * 4 + 1], hi[qq * 4 + 2], hi[qq * 4 + 3] };
        uint4 vl = { lo[qq * 4 + 0], lo[qq * 4 + 1], lo[qq * 4 + 2], lo[qq * 4 + 3] };
        *(uint4*)&xf[di]       = vh;
        *(uint4*)&xf[di + 256] = vl;
    }
    __syncthreads();

    uint4* dst = (uint4*)(ws + WS_X + (size_t)b * 32768) + tid * 8;
#pragma unroll
    for (int i = 0; i < 8; ++i) dst[i] = *(const uint4*)&xf[tid * 32 + i * 4];
}

// ---------------- V8 main kernel: 512 thr (8 waves), 64 rows/block, 1024 blocks
__global__ __launch_bounds__(512, 4) void star_mfma_v8(
    const float* __restrict__ ind,  // [65536,8]
    const char* __restrict__ ws,
    float* __restrict__ out)        // [65536,64]
{
    // 67584B shared buffer. H0 planes live epi0..phase1; H1 planes ALIAS the
    // same memory (H0 dead after phase 1, enforced by the S2 barrier).
    __shared__ __align__(16) char smem[67584];
    unsigned short* const H0hi = (unsigned short*)smem;             // [64][264]
    unsigned short* const H0lo = (unsigned short*)(smem + 33792);   // [64][264]
    unsigned short* const H1hi = (unsigned short*)smem;             // [64][136]
    unsigned short* const H1lo = (unsigned short*)(smem + 33792);   // [64][136]
    __shared__ float indS[8 * 65];

    const int tid  = threadIdx.x;
    const int w    = tid >> 6;      // wave 0..7
    const int lane = tid & 63;
    const int c    = lane & 15;
    const int q    = lane >> 4;
    const int bx   = blockIdx.x;
    const int b0   = bx * 64;
    const int mh   = w >> 2;        // phase-2 m-half (rows mh*32..+31)
    const int nt2  = w & 3;         // phase-2 n-tile

    const char* xp  = ws + WS_X;
    const char* wB0 = ws + WS_L0;
    const char* wB1 = ws + WS_L1;
    const char* wB2 = ws + WS_L2;
    const float* bias0 = (const float*)(ws + WS_B0);
    const float* bias1 = (const float*)(ws + WS_B1);
    const float* bias2 = (const float*)(ws + WS_B2);

    // indicator: 64 rows x 8 j, one value per thread; indS[j][m] padded
    indS[(tid & 7) * 65 + (tid >> 3)] = ind[(size_t)b0 * 8 + tid];

    const f32x4 z = {0.f, 0.f, 0.f, 0.f};
    f32x4 oacc[2]; oacc[0] = z; oacc[1] = z;

    __syncthreads();

    for (int jp = 0; jp < 4; ++jp) {
        // ========== phase 0 for 2 domains: X[64,512] @ W0[j][512,256] ======
        // Per kc: 8 A-loads (L1-shared across the block's 8 waves) + 4 B-pair
        // loads -> 48 MFMAs (12 per B pair). acc0 = 64 AGPRs.
        f32x4 acc0[2][4][2];   // [jj][mt][ntl]
#pragma unroll
        for (int jj = 0; jj < 2; ++jj)
#pragma unroll
            for (int mt = 0; mt < 4; ++mt)
#pragma unroll
                for (int ntl = 0; ntl < 2; ++ntl) acc0[jj][mt][ntl] = z;

        for (int kc = 0; kc < 16; ++kc) {
            Frag Ahi[4], Alo[4];
#pragma unroll
            for (int mt = 0; mt < 4; ++mt) {
                const char* ap = xp + ((size_t)((bx * 4 + mt) * 16 + kc) * 2048) + lane * 16;
                *(uint4*)Ahi[mt].u = *(const uint4*)ap;
                *(uint4*)Alo[mt].u = *(const uint4*)(ap + 1024);
            }
#pragma unroll
            for (int jj = 0; jj < 2; ++jj) {
                const int j = jp * 2 + jj;
#pragma unroll
                for (int ntl = 0; ntl < 2; ++ntl) {
                    const int nt = w * 2 + ntl;
                    const char* pb = wB0 + ((size_t)((j * 16 + kc) * 16 + nt) * 2048) + lane * 16;
                    Frag Bhi, Blo;
                    *(uint4*)Bhi.u = *(const uint4*)pb;
                    *(uint4*)Blo.u = *(const uint4*)(pb + 1024);
#pragma unroll
                    for (int mt = 0; mt < 4; ++mt) {
                        acc0[jj][mt][ntl] = __builtin_amdgcn_mfma_f32_16x16x32_bf16(Ahi[mt].v, Bhi.v, acc0[jj][mt][ntl], 0, 0, 0);
                        acc0[jj][mt][ntl] = __builtin_amdgcn_mfma_f32_16x16x32_bf16(Ahi[mt].v, Blo.v, acc0[jj][mt][ntl], 0, 0, 0);
                        acc0[jj][mt][ntl] = __builtin_amdgcn_mfma_f32_16x16x32_bf16(Alo[mt].v, Bhi.v, acc0[jj][mt][ntl], 0, 0, 0);
                    }
                }
            }
        }

        // ========== per-domain tail: epi0 -> phase1 -> epi1 -> phase2 ======
#pragma unroll
        for (int jj = 0; jj < 2; ++jj) {
            const int j = jp * 2 + jj;

            // epilogue 0: bias + relu -> hi/lo bf16 planes H0[m][k]
#pragma unroll
            for (int ntl = 0; ntl < 2; ++ntl) {
                const int k = w * 32 + ntl * 16 + c;
                const float bv = bias0[j * 256 + k];
#pragma unroll
                for (int mt = 0; mt < 4; ++mt)
#pragma unroll
                    for (int r = 0; r < 4; ++r) {
                        float v = fmaxf(acc0[jj][mt][ntl][r] + bv, 0.f);
                        unsigned short h16, l16;
                        split16(v, h16, l16);
                        const int idx = (mt * 16 + q * 4 + r) * 264 + k;
                        H0hi[idx] = h16;
                        H0lo[idx] = l16;
                    }
            }
            __syncthreads();   // S1: H0 writes -> phase-1 reads

            // phase 1: H0[64,256] @ W1[256,128]; wave w owns cols w*16..+15
            // for all 64 rows -> zero intra-block B1 duplication.
            f32x4 acc1[4];
#pragma unroll
            for (int mt = 0; mt < 4; ++mt) acc1[mt] = z;
            for (int kc = 0; kc < 8; ++kc) {
                Frag Ahi[4], Alo[4];
#pragma unroll
                for (int mt = 0; mt < 4; ++mt) {
                    const int idx = (mt * 16 + c) * 264 + kc * 32 + q * 8;
                    *(uint4*)Ahi[mt].u = *(const uint4*)&H0hi[idx];
                    *(uint4*)Alo[mt].u = *(const uint4*)&H0lo[idx];
                }
                const char* pb = wB1 + ((size_t)((j * 8 + kc) * 8 + w) * 2048) + lane * 16;
                Frag Bhi, Blo;
                *(uint4*)Bhi.u = *(const uint4*)pb;
                *(uint4*)Blo.u = *(const uint4*)(pb + 1024);
#pragma unroll
                for (int mt = 0; mt < 4; ++mt) {
                    acc1[mt] = __builtin_amdgcn_mfma_f32_16x16x32_bf16(Ahi[mt].v, Bhi.v, acc1[mt], 0, 0, 0);
                    acc1[mt] = __builtin_amdgcn_mfma_f32_16x16x32_bf16(Ahi[mt].v, Blo.v, acc1[mt], 0, 0, 0);
                    acc1[mt] = __builtin_amdgcn_mfma_f32_16x16x32_bf16(Alo[mt].v, Bhi.v, acc1[mt], 0, 0, 0);
                }
            }
            __syncthreads();   // S2: phase-1 H0 reads done BEFORE aliased H1 writes

            // epilogue 1 -> H1 planes (alias H0 memory); col k = w*16 + c
            {
                const int k = w * 16 + c;
                const float bv = bias1[j * 128 + k];
#pragma unroll
                for (int mt = 0; mt < 4; ++mt)
#pragma unroll
                    for (int r = 0; r < 4; ++r) {
                        float v = fmaxf(acc1[mt][r] + bv, 0.f);
                        unsigned short h16, l16;
                        split16(v, h16, l16);
                        const int idx = (mt * 16 + q * 4 + r) * 136 + k;
                        H1hi[idx] = h16;
                        H1lo[idx] = l16;
                    }
            }
            __syncthreads();   // S3: H1 writes -> phase-2 reads

            // phase 2: H1[64,128] @ W2[128,64]; wave (mh,nt2) owns rows
            // mh*32..+31 x cols nt2*16..+15 (2x B2 dup via L1, minor).
            f32x4 acc2[2]; acc2[0] = z; acc2[1] = z;
            for (int kc = 0; kc < 4; ++kc) {
                const char* pb = wB2 + ((size_t)((j * 4 + kc) * 4 + nt2) * 2048) + lane * 16;
                Frag Bhi, Blo;
                *(uint4*)Bhi.u = *(const uint4*)pb;
                *(uint4*)Blo.u = *(const uint4*)(pb + 1024);
#pragma unroll
                for (int mtl = 0; mtl < 2; ++mtl) {
                    Frag Ahi, Alo;
                    const int idx = ((mh * 2 + mtl) * 16 + c) * 136 + kc * 32 + q * 8;
                    *(uint4*)Ahi.u = *(const uint4*)&H1hi[idx];
                    *(uint4*)Alo.u = *(const uint4*)&H1lo[idx];
                    acc2[mtl] = __builtin_amdgcn_mfma_f32_16x16x32_bf16(Ahi.v, Bhi.v, acc2[mtl], 0, 0, 0);
                    acc2[mtl] = __builtin_amdgcn_mfma_f32_16x16x32_bf16(Ahi.v, Blo.v, acc2[mtl], 0, 0, 0);
                    acc2[mtl] = __builtin_amdgcn_mfma_f32_16x16x32_bf16(Alo.v, Bhi.v, acc2[mtl], 0, 0, 0);
                }
            }
            // epilogue 2: bias + relu + indicator mix into oacc
            {
                const float bv = bias2[j * 64 + nt2 * 16 + c];
#pragma unroll
                for (int mtl = 0; mtl < 2; ++mtl)
#pragma unroll
                    for (int r = 0; r < 4; ++r) {
                        float v = fmaxf(acc2[mtl][r] + bv, 0.f);
                        const int m = (mh * 2 + mtl) * 16 + q * 4 + r;
                        oacc[mtl][r] = fmaf(indS[j * 65 + m], v, oacc[mtl][r]);
                    }
            }
            __syncthreads();   // S4: phase-2 H1 reads done BEFORE next epi0's
                               // aliased H0 writes
        }
    }

    // store: out[b0 + (mh*2+mtl)*16 + q*4 + r][nt2*16 + c]
#pragma unroll
    for (int mtl = 0; mtl < 2; ++mtl)
#pragma unroll
        for (int r = 0; r < 4; ++r)
            out[(size_t)(b0 + (mh * 2 + mtl) * 16 + q * 4 + r) * 64 + nt2 * 16 + c] = oacc[mtl][r];
}

// ---------------- fallback (verbatim V1): 256 thr, splits x on the fly ----
__global__ __launch_bounds__(256, 3) void star_mfma_fb(
    const float* __restrict__ x,    // [65536,512]
    const float* __restrict__ ind,  // [65536,8]
    const char* __restrict__ ws,
    float* __restrict__ out)        // [65536,64]
{
    __shared__ unsigned int H0s[32 * 260];
    __shared__ unsigned int H1s[32 * 132];
    __shared__ float indS[8 * 33];

    const int tid  = threadIdx.x;
    const int w    = tid >> 6;
    const int lane = tid & 63;
    const int c    = lane & 15;
    const int q    = lane >> 4;
    const int b0   = blockIdx.x * 32;

    const char* wB0 = ws + WS_L0;
    const char* wB1 = ws + WS_L1;
    const char* wB2 = ws + WS_L2;
    const float* bias0 = (const float*)(ws + WS_B0);
    const float* bias1 = (const float*)(ws + WS_B1);
    const float* bias2 = (const float*)(ws + WS_B2);

    indS[(tid & 7) * 33 + (tid >> 3)] = ind[(size_t)b0 * 8 + tid];

    const f32x4 z = {0.f, 0.f, 0.f, 0.f};
    f32x4 oacc[2]; oacc[0] = z; oacc[1] = z;

    __syncthreads();

    for (int j = 0; j < 8; ++j) {
        f32x4 acc0[2][4];
#pragma unroll
        for (int mt = 0; mt < 2; ++mt)
#pragma unroll
            for (int ntl = 0; ntl < 4; ++ntl) acc0[mt][ntl] = z;

        for (int kc = 0; kc < 16; ++kc) {
            Frag Ahi[2], Alo[2];
#pragma unroll
            for (int mt = 0; mt < 2; ++mt) {
                const float* ap = x + (size_t)(b0 + mt * 16 + c) * 512 + kc * 32 + q * 8;
                float4 a0 = *(const float4*)ap;
                float4 a1 = *(const float4*)(ap + 4);
                splitpair(a0.x, a0.y, Ahi[mt].u[0], Alo[mt].u[0]);
                splitpair(a0.z, a0.w, Ahi[mt].u[1], Alo[mt].u[1]);
                splitpair(a1.x, a1.y, Ahi[mt].u[2], Alo[mt].u[2]);
                splitpair(a1.z, a1.w, Ahi[mt].u[3], Alo[mt].u[3]);
            }
#pragma unroll
            for (int ntl = 0; ntl < 4; ++ntl) {
                const int nt = w * 4 + ntl;
                const char* pb = wB0 + ((size_t)((j * 16 + kc) * 16 + nt) * 2048) + lane * 16;
                Frag Bhi, Blo;
                *(uint4*)Bhi.u = *(const uint4*)pb;
                *(uint4*)Blo.u = *(const uint4*)(pb + 1024);
#pragma unroll
                for (int mt = 0; mt < 2; ++mt) {
                    acc0[mt][ntl] = __builtin_amdgcn_mfma_f32_16x16x32_bf16(Ahi[mt].v, Bhi.v, acc0[mt][ntl], 0, 0, 0);
                    acc0[mt][ntl] = __builtin_amdgcn_mfma_f32_16x16x32_bf16(Ahi[mt].v, Blo.v, acc0[mt][ntl], 0, 0, 0);
                    acc0[mt][ntl] = __builtin_amdgcn_mfma_f32_16x16x32_bf16(Alo[mt].v, Bhi.v, acc0[mt][ntl], 0, 0, 0);
                }
            }
        }
#pragma unroll
        for (int ntl = 0; ntl < 4; ++ntl) {
            const float bv = bias0[j * 256 + w * 64 + ntl * 16 + c];
#pragma unroll
            for (int mt = 0; mt < 2; ++mt)
#pragma unroll
                for (int r = 0; r < 4; ++r) {
                    float v = acc0[mt][ntl][r] + bv;
                    v = fmaxf(v, 0.f);
                    H0s[(mt * 16 + q * 4 + r) * 260 + w * 64 + ntl * 16 + c] = packsplit(v);
                }
        }
        __syncthreads();

        f32x4 acc1[2][2];
#pragma unroll
        for (int mt = 0; mt < 2; ++mt)
#pragma unroll
            for (int ntl = 0; ntl < 2; ++ntl) acc1[mt][ntl] = z;

        for (int kc = 0; kc < 8; ++kc) {
            Frag Ahi[2], Alo[2];
#pragma unroll
            for (int mt = 0; mt < 2; ++mt) {
                const unsigned int* hp = &H0s[(mt * 16 + c) * 260 + kc * 32 + q * 8];
                uint4 e0 = *(const uint4*)hp;
                uint4 e1 = *(const uint4*)(hp + 4);
                unpack2(e0.x, e0.y, Ahi[mt].u[0], Alo[mt].u[0]);
                unpack2(e0.z, e0.w, Ahi[mt].u[1], Alo[mt].u[1]);
                unpack2(e1.x, e1.y, Ahi[mt].u[2], Alo[mt].u[2]);
                unpack2(e1.z, e1.w, Ahi[mt].u[3], Alo[mt].u[3]);
            }
#pragma unroll
            for (int ntl = 0; ntl < 2; ++ntl) {
                const int nt = w * 2 + ntl;
                const char* pb = wB1 + ((size_t)((j * 8 + kc) * 8 + nt) * 2048) + lane * 16;
                Frag Bhi, Blo;
                *(uint4*)Bhi.u = *(const uint4*)pb;
                *(uint4*)Blo.u = *(const uint4*)(pb + 1024);
#pragma unroll
                for (int mt = 0; mt < 2; ++mt) {
                    acc1[mt][ntl] = __builtin_amdgcn_mfma_f32_16x16x32_bf16(Ahi[mt].v, Bhi.v, acc1[mt][ntl], 0, 0, 0);
                    acc1[mt][ntl] = __builtin_amdgcn_mfma_f32_16x16x32_bf16(Ahi[mt].v, Blo.v, acc1[mt][ntl], 0, 0, 0);
                    acc1[mt][ntl] = __builtin_amdgcn_mfma_f32_16x16x32_bf16(Alo[mt].v, Bhi.v, acc1[mt][ntl], 0, 0, 0);
                }
            }
        }
#pragma unroll
        for (int ntl = 0; ntl < 2; ++ntl) {
            const float bv = bias1[j * 128 + w * 32 + ntl * 16 + c];
#pragma unroll
            for (int mt = 0; mt < 2; ++mt)
#pragma unroll
                for (int r = 0; r < 4; ++r) {
                    float v = acc1[mt][ntl][r] + bv;
                    v = fmaxf(v, 0.f);
                    H1s[(mt * 16 + q * 4 + r) * 132 + w * 32 + ntl * 16 + c] = packsplit(v);
                }
        }
        __syncthreads();

        f32x4 acc2[2]; acc2[0] = z; acc2[1] = z;

        for (int kc = 0; kc < 4; ++kc) {
            Frag Ahi[2], Alo[2];
#pragma unroll
            for (int mt = 0; mt < 2; ++mt) {
                const unsigned int* hp = &H1s[(mt * 16 + c) * 132 + kc * 32 + q * 8];
                uint4 e0 = *(const uint4*)hp;
                uint4 e1 = *(const uint4*)(hp + 4);
                unpack2(e0.x, e0.y, Ahi[mt].u[0], Alo[mt].u[0]);
                unpack2(e0.z, e0.w, Ahi[mt].u[1], Alo[mt].u[1]);
                unpack2(e1.x, e1.y, Ahi[mt].u[2], Alo[mt].u[2]);
                unpack2(e1.z, e1.w, Ahi[mt].u[3], Alo[mt].u[3]);
            }
            const char* pb = wB2 + ((size_t)((j * 4 + kc) * 4 + w) * 2048) + lane * 16;
            Frag Bhi, Blo;
            *(uint4*)Bhi.u = *(const uint4*)pb;
            *(uint4*)Blo.u = *(const uint4*)(pb + 1024);
#pragma unroll
            for (int mt = 0; mt < 2; ++mt) {
                acc2[mt] = __builtin_amdgcn_mfma_f32_16x16x32_bf16(Ahi[mt].v, Bhi.v, acc2[mt], 0, 0, 0);
                acc2[mt] = __builtin_amdgcn_mfma_f32_16x16x32_bf16(Ahi[mt].v, Blo.v, acc2[mt], 0, 0, 0);
                acc2[mt] = __builtin_amdgcn_mfma_f32_16x16x32_bf16(Alo[mt].v, Bhi.v, acc2[mt], 0, 0, 0);
            }
        }
        {
            const float bv = bias2[j * 64 + w * 16 + c];
#pragma unroll
            for (int mt = 0; mt < 2; ++mt)
#pragma unroll
                for (int r = 0; r < 4; ++r) {
                    float v = acc2[mt][r] + bv;
                    v = fmaxf(v, 0.f);
                    oacc[mt][r] = fmaf(indS[j * 33 + mt * 16 + q * 4 + r], v, oacc[mt][r]);
                }
        }
    }

#pragma unroll
    for (int mt = 0; mt < 2; ++mt)
#pragma unroll
        for (int r = 0; r < 4; ++r)
            out[(size_t)(b0 + mt * 16 + q * 4 + r) * 64 + w * 16 + c] = oacc[mt][r];
}

} // namespace

extern "C" void kernel_launch(void* const* d_in, const int* in_sizes, int n_in,
                              void* d_out, int out_size, void* d_ws, size_t ws_size,
                              hipStream_t stream) {
    const float* x   = (const float*)d_in[0];
    const float* ind = (const float*)d_in[1];
    const float* sk0 = (const float*)d_in[2];
    const float* sb0 = (const float*)d_in[3];
    const float* dk0 = (const float*)d_in[4];
    const float* db0 = (const float*)d_in[5];
    const float* sk1 = (const float*)d_in[6];
    const float* sb1 = (const float*)d_in[7];
    const float* dk1 = (const float*)d_in[8];
    const float* db1 = (const float*)d_in[9];
    const float* sk2 = (const float*)d_in[10];
    const float* sb2 = (const float*)d_in[11];
    const float* dk2 = (const float*)d_in[12];
    const float* db2 = (const float*)d_in[13];
    char* ws   = (char*)d_ws;
    float* out = (float*)d_out;

    prep_ws<<<dim3((PREP_TOTAL + 255) / 256), dim3(256), 0, stream>>>(
        sk0, dk0, sk1, dk1, sk2, dk2, sb0, db0, sb1, db1, sb2, db2, ws);

    if (ws_size >= WS_TOTAL_BIG) {
        prep_xsplit<<<dim3(4096), dim3(256), 0, stream>>>(x, ws);
        star_mfma_v8<<<dim3(1024), dim3(512), 0, stream>>>(ind, ws, out);
    } else {
        star_mfma_fb<<<dim3(2048), dim3(256), 0, stream>>>(x, ind, ws, out);
    }
}